// Round 1
// baseline (4647.702 us; speedup 1.0000x reference)
//
#include <hip/hip_runtime.h>
#include <math.h>
#include <stdint.h>

#define BATCH 8
#define NTOK  4096
#define DIM   256
#define SK    256
#define QT    64
#define KT    64
#define KC    64
#define KCP   (KC + 4)   // +4 floats pad: breaks 256B row stride bank conflicts

// ---------------- threefry2x32 (JAX partitionable counter mode) ----------------
__device__ __forceinline__ uint32_t rotl32(uint32_t v, uint32_t r) {
  return (v << r) | (v >> (32u - r));
}

__device__ __forceinline__ void tf_round4(uint32_t& x0, uint32_t& x1,
                                          uint32_t r0, uint32_t r1,
                                          uint32_t r2, uint32_t r3) {
  x0 += x1; x1 = rotl32(x1, r0); x1 ^= x0;
  x0 += x1; x1 = rotl32(x1, r1); x1 ^= x0;
  x0 += x1; x1 = rotl32(x1, r2); x1 ^= x0;
  x0 += x1; x1 = rotl32(x1, r3); x1 ^= x0;
}

// key = jax.random.key(42) -> (k0, k1) = (0, 42)
__device__ __forceinline__ uint32_t threefry_bits32(uint32_t c_hi, uint32_t c_lo) {
  const uint32_t k0 = 0u, k1 = 42u;
  const uint32_t k2 = k0 ^ k1 ^ 0x1BD11BDAu;
  uint32_t x0 = c_hi + k0;
  uint32_t x1 = c_lo + k1;
  tf_round4(x0, x1, 13u, 15u, 26u, 6u);  x0 += k1; x1 += k2 + 1u;
  tf_round4(x0, x1, 17u, 29u, 16u, 24u); x0 += k2; x1 += k0 + 2u;
  tf_round4(x0, x1, 13u, 15u, 26u, 6u);  x0 += k0; x1 += k1 + 3u;
  tf_round4(x0, x1, 17u, 29u, 16u, 24u); x0 += k1; x1 += k2 + 4u;
  tf_round4(x0, x1, 13u, 15u, 26u, 6u);  x0 += k2; x1 += k0 + 5u;
  // partitionable 32-bit output: xor of the two halves
  return x0 ^ x1;
}

// ---------------- kernel 1: row squared norms (f64) ----------------
__global__ __launch_bounds__(256) void rowsq_kernel(const float* __restrict__ x,
                                                    double* __restrict__ sq) {
  int wave = threadIdx.x >> 6;
  int lane = threadIdx.x & 63;
  int row  = (blockIdx.x << 2) + wave;           // [0, BATCH*NTOK)
  const float* xr = x + (size_t)row * DIM;
  double acc = 0.0;
#pragma unroll
  for (int j = 0; j < DIM; j += 64) {
    double v = (double)xr[j + lane];
    acc += v * v;
  }
#pragma unroll
  for (int off = 32; off > 0; off >>= 1)
    acc += __shfl_down(acc, off, 64);
  if (lane == 0) sq[row] = acc;
}

// ---------------- kernel 2: all-pairs dot (f64 acc) + per-query 5th-NN d2 ------
__global__ __launch_bounds__(256) void knn_kernel(const float* __restrict__ x,
                                                  const double* __restrict__ sq,
                                                  double* __restrict__ dk2) {
  __shared__ __align__(16) float As[QT * KCP];        // ~17.4 KB
  __shared__ __align__(16) float Bs[KT * KCP];        // ~17.4 KB
  __shared__ double Cs[QT * (KT + 1)];                // 33.3 KB (+1 pad per row)

  const int b  = blockIdx.x / (NTOK / QT);
  const int qt = blockIdx.x % (NTOK / QT);
  const int q0 = qt * QT;
  const float*  xb  = x  + (size_t)b * NTOK * DIM;
  const double* sqb = sq + (size_t)b * NTOK;

  const int t  = threadIdx.x;
  const int tx = t & 15;
  const int ty = t >> 4;

  double t5[5] = {1e300, 1e300, 1e300, 1e300, 1e300};  // ascending; t5[4] = 5th smallest

  for (int mt = 0; mt < NTOK / KT; ++mt) {
    const int m0 = mt * KT;
    double acc[4][4];
#pragma unroll
    for (int i = 0; i < 4; ++i)
#pragma unroll
      for (int j = 0; j < 4; ++j) acc[i][j] = 0.0;

    for (int kb = 0; kb < DIM; kb += KC) {
      __syncthreads();
#pragma unroll
      for (int e = 0; e < 16; ++e) {
        int li = t + e * 256;
        int r = li >> 6, c = li & 63;
        As[r * KCP + c] = xb[(size_t)(q0 + r) * DIM + kb + c];
        Bs[r * KCP + c] = xb[(size_t)(m0 + r) * DIM + kb + c];
      }
      __syncthreads();
#pragma unroll
      for (int kk = 0; kk < KC; kk += 4) {
        float4 av[4], bv[4];
#pragma unroll
        for (int i = 0; i < 4; ++i) av[i] = *(const float4*)&As[(ty * 4 + i) * KCP + kk];
#pragma unroll
        for (int j = 0; j < 4; ++j) bv[j] = *(const float4*)&Bs[(tx * 4 + j) * KCP + kk];
#pragma unroll
        for (int i = 0; i < 4; ++i)
#pragma unroll
          for (int j = 0; j < 4; ++j) {
            acc[i][j] += (double)av[i].x * (double)bv[j].x;
            acc[i][j] += (double)av[i].y * (double)bv[j].y;
            acc[i][j] += (double)av[i].z * (double)bv[j].z;
            acc[i][j] += (double)av[i].w * (double)bv[j].w;
          }
      }
    }
    __syncthreads();
#pragma unroll
    for (int i = 0; i < 4; ++i)
#pragma unroll
      for (int j = 0; j < 4; ++j)
        Cs[(ty * 4 + i) * (KT + 1) + tx * 4 + j] = acc[i][j];
    __syncthreads();
    if (t < QT) {
      const int qg = q0 + t;
      const double sqq = sqb[qg];
      for (int mm = 0; mm < KT; ++mm) {
        const int mg = m0 + mm;
        if (mg == qg) continue;                       // diag = inf in reference
        double d2 = sqq + sqb[mg] - 2.0 * Cs[t * (KT + 1) + mm];
        if (d2 < 0.0) d2 = 0.0;                       // jnp.maximum(d2, 0)
        if (d2 < t5[4]) {
          t5[4] = d2;
#pragma unroll
          for (int j2 = 4; j2 > 0; --j2) {
            if (t5[j2] < t5[j2 - 1]) { double tmp = t5[j2]; t5[j2] = t5[j2 - 1]; t5[j2 - 1] = tmp; }
          }
        }
      }
    }
  }
  if (t < QT) dk2[(size_t)b * NTOK + q0 + t] = t5[4];
}

// ---------------- kernel 3: gumbel + score (f64) ----------------
__global__ __launch_bounds__(256) void score_kernel(const double* __restrict__ dk2,
                                                    double* __restrict__ scores) {
  const int i = blockIdx.x * 256 + threadIdx.x;       // flat [0, BATCH*NTOK)
  // partitionable counter mode: element i -> threefry(key, (hi32(i), lo32(i)))
  const uint32_t bits = threefry_bits32(0u, (uint32_t)i);
  const uint32_t fb = (bits >> 9) | 0x3F800000u;
  float uf = __uint_as_float(fb) - 1.0f;              // [0, 1)
  const float tiny = 1.17549435082228750797e-38f;     // np.finfo(f32).tiny
  uf += tiny;                                          // floats*(max-min)+min, f32
  if (uf < tiny) uf = tiny;                            // lax.max(minval, .)
  const double g = -log(-log((double)uf));
  const double w = sqrt(dk2[i] + 1e-12);
  scores[i] = log(w + 1e-12) + g;
}

// ---------------- kernel 4: per-batch stable top-256 + gather ----------------
__global__ __launch_bounds__(256) void topk_gather_kernel(const float* __restrict__ x,
                                                          const double* __restrict__ scores,
                                                          float* __restrict__ out) {
  __shared__ double s[NTOK];                           // 32 KB
  __shared__ double rs[4];
  __shared__ int    ri[4];
  __shared__ int    sel[SK];
  const int b = blockIdx.x;
  const int t = threadIdx.x;

  for (int j = t; j < NTOK; j += 256) s[j] = scores[(size_t)b * NTOK + j];
  __syncthreads();

  for (int it = 0; it < SK; ++it) {
    double bs = -INFINITY; int bi = NTOK;
    for (int j = t; j < NTOK; j += 256) {
      double v = s[j];
      if (v > bs || (v == bs && j < bi)) { bs = v; bi = j; }
    }
#pragma unroll
    for (int off = 32; off > 0; off >>= 1) {
      double os = __shfl_down(bs, off, 64);
      int    oi = __shfl_down(bi, off, 64);
      if (os > bs || (os == bs && oi < bi)) { bs = os; bi = oi; }
    }
    if ((t & 63) == 0) { rs[t >> 6] = bs; ri[t >> 6] = bi; }
    __syncthreads();
    if (t == 0) {
#pragma unroll
      for (int wv = 1; wv < 4; ++wv)
        if (rs[wv] > bs || (rs[wv] == bs && ri[wv] < bi)) { bs = rs[wv]; bi = ri[wv]; }
      sel[it] = bi;
      s[bi] = -INFINITY;                               // remove from candidates
    }
    __syncthreads();
  }

  // gather: out[b, it, :] = x[b, sel[it], :]   (bitwise f32 copy)
  for (int it = 0; it < SK; ++it) {
    const int src = sel[it];
    out[((size_t)b * SK + it) * DIM + t] = x[((size_t)b * NTOK + src) * DIM + t];
  }
  if (b == 0 && t == 0) out[(size_t)BATCH * SK * DIM] = 0.0f;  // second output: 0.0
}

extern "C" void kernel_launch(void* const* d_in, const int* in_sizes, int n_in,
                              void* d_out, int out_size, void* d_ws, size_t ws_size,
                              hipStream_t stream) {
  const float* x = (const float*)d_in[0];
  float* out = (float*)d_out;

  double* sq     = (double*)d_ws;                      // BATCH*NTOK f64 = 256 KB
  double* dk2    = sq  + (size_t)BATCH * NTOK;         // 256 KB
  double* scores = dk2 + (size_t)BATCH * NTOK;         // 256 KB

  rowsq_kernel<<<BATCH * NTOK / 4, 256, 0, stream>>>(x, sq);
  knn_kernel<<<BATCH * (NTOK / QT), 256, 0, stream>>>(x, sq, dk2);
  score_kernel<<<BATCH * NTOK / 256, 256, 0, stream>>>(dk2, scores);
  topk_gather_kernel<<<BATCH, 256, 0, stream>>>(x, scores, out);
}

// Round 2
// 994.784 us; speedup vs baseline: 4.6721x; 4.6721x over previous
//
#include <hip/hip_runtime.h>
#include <hip/hip_bf16.h>
#include <math.h>
#include <stdint.h>

#define BATCH 8
#define NTOK  4096
#define DIM   256
#define SK    256
#define BQ    64      // q rows per block
#define BM    128     // m cols per m-tile iteration
#define CAND  40      // max candidates kept per query (4 slices x top-10)

typedef __attribute__((ext_vector_type(8))) short short8;   // 8 bf16
typedef __attribute__((ext_vector_type(4))) float float4v;  // 4 f32 acc

#define GLOAD_LDS16(gp, lp)                                                    \
  __builtin_amdgcn_global_load_lds(                                            \
      (const __attribute__((address_space(1))) unsigned int*)(gp),             \
      (__attribute__((address_space(3))) unsigned int*)(lp), 16, 0, 0)

// ---------------- threefry2x32 (JAX partitionable counter mode) ----------------
__device__ __forceinline__ uint32_t rotl32(uint32_t v, uint32_t r) {
  return (v << r) | (v >> (32u - r));
}
__device__ __forceinline__ void tf_round4(uint32_t& x0, uint32_t& x1,
                                          uint32_t r0, uint32_t r1,
                                          uint32_t r2, uint32_t r3) {
  x0 += x1; x1 = rotl32(x1, r0); x1 ^= x0;
  x0 += x1; x1 = rotl32(x1, r1); x1 ^= x0;
  x0 += x1; x1 = rotl32(x1, r2); x1 ^= x0;
  x0 += x1; x1 = rotl32(x1, r3); x1 ^= x0;
}
__device__ __forceinline__ uint32_t threefry_bits32(uint32_t c_hi, uint32_t c_lo) {
  const uint32_t k0 = 0u, k1 = 42u;
  const uint32_t k2 = k0 ^ k1 ^ 0x1BD11BDAu;
  uint32_t x0 = c_hi + k0;
  uint32_t x1 = c_lo + k1;
  tf_round4(x0, x1, 13u, 15u, 26u, 6u);  x0 += k1; x1 += k2 + 1u;
  tf_round4(x0, x1, 17u, 29u, 16u, 24u); x0 += k2; x1 += k0 + 2u;
  tf_round4(x0, x1, 13u, 15u, 26u, 6u);  x0 += k0; x1 += k1 + 3u;
  tf_round4(x0, x1, 17u, 29u, 16u, 24u); x0 += k1; x1 += k2 + 4u;
  tf_round4(x0, x1, 13u, 15u, 26u, 6u);  x0 += k2; x1 += k0 + 5u;
  return x0 ^ x1;
}

// ---------------- kernel 1: bf16 hi/lo split + row squared norms ----------------
__global__ __launch_bounds__(256) void split_rowsq_kernel(
    const float* __restrict__ x, unsigned short* __restrict__ xh,
    unsigned short* __restrict__ xl, double* __restrict__ sq,
    float* __restrict__ sqf) {
  const int row  = blockIdx.x * 4 + (threadIdx.x >> 6);   // [0, BATCH*NTOK)
  const int lane = threadIdx.x & 63;
  const float* xr = x + (size_t)row * DIM;
  double acc = 0.0;
#pragma unroll
  for (int i = 0; i < 4; ++i) {
    const float v = xr[lane + i * 64];
    __hip_bfloat16 h = __float2bfloat16(v);          // RNE
    const float hf = __bfloat162float(h);
    const float lo = v - hf;                         // exact residual
    __hip_bfloat16 h2 = __float2bfloat16(lo);
    xh[(size_t)row * DIM + lane + i * 64] = *(unsigned short*)&h;
    xl[(size_t)row * DIM + lane + i * 64] = *(unsigned short*)&h2;
    acc += (double)v * (double)v;
  }
#pragma unroll
  for (int off = 32; off > 0; off >>= 1) acc += __shfl_down(acc, off, 64);
  if (lane == 0) { sq[row] = acc; sqf[row] = (float)acc; }
}

// ---------------- kernel 2: MFMA 3-pass bf16-split GEMM + candidate top-10 ------
__global__ __launch_bounds__(256, 2) void gemm_knn_kernel(
    const unsigned short* __restrict__ xh, const unsigned short* __restrict__ xl,
    const float* __restrict__ sqf, int* __restrict__ cand) {
  __shared__ unsigned short Ap[2][BQ][DIM];          // 64 KB persistent A panel
  __shared__ union {
    unsigned short B[2][BM][32];                     // 16 KB: B k-slice hi/lo
    float C[BQ][64];                                 // 16 KB: dot half-tile
    struct { float mv[256][10]; unsigned short mi[256][10]; } M;  // 15.3 KB
  } U;

  const int b  = blockIdx.x >> 6;                    // 64 q-tiles per batch
  const int qt = blockIdx.x & 63;
  const int q0 = qt * BQ;
  const int t  = threadIdx.x;
  const int w  = t >> 6;
  const int l  = t & 63;
  const int lr = l & 15;
  const int kq = (l >> 4) * 8;

  const unsigned short* xhb = xh + (size_t)b * NTOK * DIM;
  const unsigned short* xlb = xl + (size_t)b * NTOK * DIM;
  const float* sqb = sqf + b * NTOK;

  // stage persistent A panel (64 rows x 256 cols, hi then lo) via global_load_lds
#pragma unroll
  for (int p = 0; p < 2; ++p) {
    const unsigned short* src = p ? xlb : xhb;
#pragma unroll
    for (int is = 0; is < 8; ++is) {
      const int row = is * 8 + (t >> 5);
      const int col = (t & 31) * 8;
      GLOAD_LDS16(src + (size_t)(q0 + row) * DIM + col,
                  (char*)&Ap[0][0][0] + p * 32768 + is * 4096 + t * 16);
    }
  }

  const int qg_t = q0 + (t & 63);                    // this thread's scan query
  const float sqq = sqb[qg_t];

  float tv[10]; int ti[10];
#pragma unroll
  for (int j = 0; j < 10; ++j) { tv[j] = 3.0e38f; ti[j] = 0; }

  for (int mt = 0; mt < NTOK / BM; ++mt) {
    const int m0 = mt * BM;
    float4v acc[4][2];
#pragma unroll
    for (int i = 0; i < 4; ++i)
#pragma unroll
      for (int j = 0; j < 2; ++j) acc[i][j] = (float4v){0.f, 0.f, 0.f, 0.f};

    for (int kb = 0; kb < DIM; kb += 32) {
      __syncthreads();                                // prior use of U done
#pragma unroll
      for (int p = 0; p < 2; ++p) {
        const unsigned short* src = p ? xlb : xhb;
#pragma unroll
        for (int is = 0; is < 2; ++is) {
          const int row = is * 64 + (t >> 2);
          const int col = kb + (t & 3) * 8;
          GLOAD_LDS16(src + (size_t)(m0 + row) * DIM + col,
                      (char*)&U.B[0][0][0] + p * 8192 + is * 4096 + t * 16);
        }
      }
      __syncthreads();                                // loads landed

      short8 af[2][4], bf[2][2];
#pragma unroll
      for (int p = 0; p < 2; ++p)
#pragma unroll
        for (int i = 0; i < 4; ++i)
          af[p][i] = *(const short8*)&Ap[p][i * 16 + lr][kb + kq];
#pragma unroll
      for (int p = 0; p < 2; ++p)
#pragma unroll
        for (int j = 0; j < 2; ++j)
          bf[p][j] = *(const short8*)&U.B[p][w * 32 + j * 16 + lr][kq];

#pragma unroll
      for (int i = 0; i < 4; ++i)
#pragma unroll
        for (int j = 0; j < 2; ++j) {
          acc[i][j] = __builtin_amdgcn_mfma_f32_16x16x32_bf16(af[0][i], bf[0][j], acc[i][j], 0, 0, 0);
          acc[i][j] = __builtin_amdgcn_mfma_f32_16x16x32_bf16(af[0][i], bf[1][j], acc[i][j], 0, 0, 0);
          acc[i][j] = __builtin_amdgcn_mfma_f32_16x16x32_bf16(af[1][i], bf[0][j], acc[i][j], 0, 0, 0);
        }
    }

    // epilogue: two 64x64 halves through U.C (overlays U.B)
#pragma unroll
    for (int h = 0; h < 2; ++h) {
      __syncthreads();
      if ((w >> 1) == h) {
#pragma unroll
        for (int i = 0; i < 4; ++i)
#pragma unroll
          for (int j = 0; j < 2; ++j)
#pragma unroll
            for (int r = 0; r < 4; ++r) {
              const int row = i * 16 + (l >> 4) * 4 + r;
              const int col = (w & 1) * 32 + j * 16 + lr;   // within half
              U.C[row][(col + row) & 63] = acc[i][j][r];
            }
      }
      __syncthreads();
      {
        const int q = t & 63;
        const int s = t >> 6;
        for (int i2 = 0; i2 < 16; ++i2) {
          const int ml = s * 16 + i2;                  // within half
          const int mg = m0 + h * 64 + ml;             // global token index
          if (mg == qg_t - b * 0 && (q0 + q) == mg) {} // (placeholder, real check below)
          if (mg == (q0 + q)) continue;                // exclude self
          const float dot = U.C[q][(ml + q) & 63];
          const float d2a = sqq + sqb[mg] - 2.0f * dot;
          if (d2a < tv[9]) {
            tv[9] = d2a; ti[9] = mg;
#pragma unroll
            for (int k2 = 9; k2 > 0; --k2)
              if (tv[k2] < tv[k2 - 1]) {
                float tf2 = tv[k2]; tv[k2] = tv[k2 - 1]; tv[k2 - 1] = tf2;
                int tix = ti[k2]; ti[k2] = ti[k2 - 1]; ti[k2 - 1] = tix;
              }
          }
        }
      }
    }
  }

  // merge: dump per-thread top-10, then 64 threads build candidate lists
  __syncthreads();
#pragma unroll
  for (int j = 0; j < 10; ++j) { U.M.mv[t][j] = tv[j]; U.M.mi[t][j] = (unsigned short)ti[j]; }
  __syncthreads();
  if (t < 64) {
    const int q = t;
    float t5[5] = {3.0e38f, 3.0e38f, 3.0e38f, 3.0e38f, 3.0e38f};
    for (int s = 0; s < 4; ++s)
      for (int j = 0; j < 10; ++j) {
        const float v = U.M.mv[q + s * 64][j];
        if (v < t5[4]) {
          t5[4] = v;
#pragma unroll
          for (int k2 = 4; k2 > 0; --k2)
            if (t5[k2] < t5[k2 - 1]) { float tf2 = t5[k2]; t5[k2] = t5[k2 - 1]; t5[k2 - 1] = tf2; }
        }
      }
    const float T = t5[4] + 0.5f;                     // margin > 2*eps bound
    int cnt = 0, ov = 0;
    int* cq = cand + (size_t)(b * NTOK + q0 + q) * (CAND + 4);
    for (int s = 0; s < 4; ++s) {
      if (U.M.mv[q + s * 64][9] < T) ov = 1;          // slice may hide candidates
      for (int j = 0; j < 10; ++j) {
        const float v = U.M.mv[q + s * 64][j];
        if (v <= T && cnt < CAND) { cq[1 + cnt] = (int)U.M.mi[q + s * 64][j]; ++cnt; }
      }
    }
    cq[0] = ov ? -1 : cnt;
  }
}

// ---------------- kernel 3: exact f64 kNN distance on candidates ----------------
__global__ __launch_bounds__(256) void exact_knn_kernel(
    const float* __restrict__ x, const int* __restrict__ cand,
    double* __restrict__ dk2) {
  const int qg = blockIdx.x * 4 + (threadIdx.x >> 6);   // [0, BATCH*NTOK)
  const int l  = threadIdx.x & 63;
  const int b  = qg >> 12;
  const int q  = qg & (NTOK - 1);
  const float* xb = x + (size_t)b * NTOK * DIM;
  const int* cq = cand + (size_t)qg * (CAND + 4);
  const int cnt = cq[0];

  double xq[4];
#pragma unroll
  for (int i = 0; i < 4; ++i) xq[i] = (double)xb[(size_t)q * DIM + l + i * 64];

  double t5[5] = {1e300, 1e300, 1e300, 1e300, 1e300};
  const int n_iter = (cnt >= 0) ? cnt : NTOK;
  for (int c = 0; c < n_iter; ++c) {
    int m;
    if (cnt >= 0) m = cq[1 + c];
    else { m = c; if (m == q) continue; }
    double acc = 0.0;
#pragma unroll
    for (int i = 0; i < 4; ++i) {
      const double d = xq[i] - (double)xb[(size_t)m * DIM + l + i * 64];
      acc += d * d;
    }
#pragma unroll
    for (int off = 32; off > 0; off >>= 1) acc += __shfl_xor(acc, off, 64);
    if (acc < t5[4]) {
      t5[4] = acc;
#pragma unroll
      for (int k2 = 4; k2 > 0; --k2)
        if (t5[k2] < t5[k2 - 1]) { double tmp = t5[k2]; t5[k2] = t5[k2 - 1]; t5[k2 - 1] = tmp; }
    }
  }
  if (l == 0) dk2[qg] = t5[4];
}

// ---------------- kernel 4: gumbel + score (f64) ----------------
__global__ __launch_bounds__(256) void score_kernel(const double* __restrict__ dk2,
                                                    double* __restrict__ scores) {
  const int i = blockIdx.x * 256 + threadIdx.x;
  const uint32_t bits = threefry_bits32(0u, (uint32_t)i);
  const uint32_t fb = (bits >> 9) | 0x3F800000u;
  float uf = __uint_as_float(fb) - 1.0f;
  const float tiny = 1.17549435082228750797e-38f;
  uf += tiny;
  if (uf < tiny) uf = tiny;
  const double g = -log(-log((double)uf));
  const double w = sqrt(dk2[i] + 1e-12);
  scores[i] = log(w + 1e-12) + g;
}

// ---------------- kernel 5: per-batch bitonic full sort -> top-256 idx ----------
__global__ __launch_bounds__(256) void sort_topk_kernel(
    const double* __restrict__ scores, int* __restrict__ sel) {
  __shared__ unsigned long long ko[NTOK];              // 32 KB
  __shared__ int ki[NTOK];                             // 16 KB
  const int b = blockIdx.x;
  const int t = threadIdx.x;
  for (int i = t; i < NTOK; i += 256) {
    const double s = scores[(size_t)b * NTOK + i];
    unsigned long long u = (unsigned long long)__double_as_longlong(s);
    u = (u & 0x8000000000000000ull) ? ~u : (u | 0x8000000000000000ull);
    ko[i] = u; ki[i] = i;
  }
  __syncthreads();
  for (int k = 2; k <= NTOK; k <<= 1) {
    for (int j = k >> 1; j > 0; j >>= 1) {
      for (int base = 0; base < NTOK; base += 256) {
        const int i = base + t;
        const int p = i ^ j;
        if (p > i) {
          const bool up = (i & k) == 0;                // up-blocks sort descending
          unsigned long long a = ko[i], c = ko[p];
          int ia = ki[i], ic = ki[p];
          const bool p_beats = (c > a) || (c == a && ic < ia);
          const bool i_beats = (a > c) || (a == c && ia < ic);
          const bool sw = up ? p_beats : i_beats;
          if (sw) { ko[i] = c; ko[p] = a; ki[i] = ic; ki[p] = ia; }
        }
      }
      __syncthreads();
    }
  }
  if (t < SK) sel[b * SK + t] = ki[t];
}

// ---------------- kernel 6: gather sampled rows ----------------
__global__ __launch_bounds__(256) void gather_kernel(const float* __restrict__ x,
                                                     const int* __restrict__ sel,
                                                     float* __restrict__ out) {
  const int blk = blockIdx.x;                          // 8*256 blocks
  const int b = blk >> 8;
  const int r = blk & 255;
  const int t = threadIdx.x;
  const int src = sel[b * SK + r];
  out[((size_t)(b * SK + r)) * DIM + t] = x[((size_t)(b * NTOK + src)) * DIM + t];
  if (blk == 0 && t == 0) out[(size_t)BATCH * SK * DIM] = 0.0f;  // 2nd output: 0.0
}

extern "C" void kernel_launch(void* const* d_in, const int* in_sizes, int n_in,
                              void* d_out, int out_size, void* d_ws, size_t ws_size,
                              hipStream_t stream) {
  const float* x = (const float*)d_in[0];
  float* out = (float*)d_out;
  char* ws = (char*)d_ws;

  double* sq      = (double*)(ws + 0);                 // 256 KB
  double* dk2     = (double*)(ws + 262144);            // 256 KB
  double* scores  = (double*)(ws + 524288);            // 256 KB
  float*  sqf     = (float*)(ws + 786432);             // 128 KB
  int*    sel     = (int*)(ws + 917504);               // 8 KB
  unsigned short* xh = (unsigned short*)(ws + 1048576);    // 16 MB
  unsigned short* xl = (unsigned short*)(ws + 17825792);   // 16 MB
  int*    cand    = (int*)(ws + 34603008);             // 5.8 MB  (total ~40 MB)

  split_rowsq_kernel<<<BATCH * NTOK / 4, 256, 0, stream>>>(x, xh, xl, sq, sqf);
  gemm_knn_kernel<<<BATCH * (NTOK / BQ), 256, 0, stream>>>(xh, xl, sqf, cand);
  exact_knn_kernel<<<BATCH * NTOK / 4, 256, 0, stream>>>(x, cand, dk2);
  score_kernel<<<BATCH * NTOK / 256, 256, 0, stream>>>(dk2, scores);
  sort_topk_kernel<<<BATCH, 256, 0, stream>>>(scores, sel);
  gather_kernel<<<BATCH * SK, 256, 0, stream>>>(x, sel, out);
}